// Round 1
// baseline (199.690 us; speedup 1.0000x reference)
//
#include <hip/hip_runtime.h>

#define NCLS 10
#define ACC_STRIDE 64   // floats: 256 B per accumulator slot -> atomics spread over L2 channels

// ws layout: slot v in [0,20): v<10 -> sum for class v ; v>=10 -> count for class v-10
// each slot at ws[v * ACC_STRIDE]

__global__ __launch_bounds__(256) void loss_main_kernel(
    const float* __restrict__ outputs,
    const float* __restrict__ targets,
    const int*   __restrict__ mask,
    float* __restrict__ ws,
    int n4)
{
    float sum[NCLS];
    float cnt[NCLS];
#pragma unroll
    for (int c = 0; c < NCLS; ++c) { sum[c] = 0.0f; cnt[c] = 0.0f; }

    const float4* o4 = (const float4*)outputs;
    const float4* t4 = (const float4*)targets;
    const int4*   m4 = (const int4*)mask;

    int tid    = blockIdx.x * blockDim.x + threadIdx.x;
    int stride = gridDim.x * blockDim.x;

    for (int i = tid; i < n4; i += stride) {
        float4 o = o4[i];
        float4 t = t4[i];
        int4   m = m4[i];

        float od[4] = {o.x, o.y, o.z, o.w};
        float td[4] = {t.x, t.y, t.z, t.w};
        int   md[4] = {m.x, m.y, m.z, m.w};

#pragma unroll
        for (int j = 0; j < 4; ++j) {
            float d  = od[j] - td[j];
            float sq = d * d;
            // invalid pixels -> dummy class NCLS (never matches 0..9)
            int cls = (md[j] == 1) ? (int)td[j] : NCLS;
#pragma unroll
            for (int c = 0; c < NCLS; ++c) {
                float match = (cls == c) ? 1.0f : 0.0f;
                cnt[c] += match;
                sum[c] = fmaf(match, sq, sum[c]);
            }
        }
    }

    // --- wave (64-lane) reduction per class ---
#pragma unroll
    for (int c = 0; c < NCLS; ++c) {
#pragma unroll
        for (int off = 32; off > 0; off >>= 1) {
            sum[c] += __shfl_down(sum[c], off, 64);
            cnt[c] += __shfl_down(cnt[c], off, 64);
        }
    }

    // --- cross-wave reduction in LDS (4 waves / 256-thread block) ---
    __shared__ float ls[4][2 * NCLS];
    int wave = threadIdx.x >> 6;
    int lane = threadIdx.x & 63;
    if (lane == 0) {
#pragma unroll
        for (int c = 0; c < NCLS; ++c) {
            ls[wave][c]        = sum[c];
            ls[wave][NCLS + c] = cnt[c];
        }
    }
    __syncthreads();

    if (threadIdx.x < 2 * NCLS) {
        float v = ls[0][threadIdx.x] + ls[1][threadIdx.x]
                + ls[2][threadIdx.x] + ls[3][threadIdx.x];
        atomicAdd(&ws[threadIdx.x * ACC_STRIDE], v);
    }
}

__global__ __launch_bounds__(64) void loss_final_kernel(
    const float* __restrict__ ws,
    float* __restrict__ out)
{
    int lane = threadIdx.x;   // single wave
    float le = 0.0f;
    if (lane < NCLS) {
        float s  = ws[lane * ACC_STRIDE];
        float cn = ws[(NCLS + lane) * ACC_STRIDE];
        le = (cn > 0.0f) ? (s / fmaxf(cn, 1.0f)) : 0.0f;
        out[1 + lane]  = le;        // loss_each
        out[11 + lane] = cn;        // class_n
    }
    float w = 0.1f * le;            // WEIGHT = 0.1 per class
#pragma unroll
    for (int off = 32; off > 0; off >>= 1) w += __shfl_down(w, off, 64);
    if (lane == 0) out[0] = w;      // loss
}

extern "C" void kernel_launch(void* const* d_in, const int* in_sizes, int n_in,
                              void* d_out, int out_size, void* d_ws, size_t ws_size,
                              hipStream_t stream)
{
    const float* outputs = (const float*)d_in[0];
    const float* targets = (const float*)d_in[1];
    const int*   mask    = (const int*)d_in[2];
    float* out = (float*)d_out;
    float* ws  = (float*)d_ws;

    int n  = in_sizes[0];
    int n4 = n / 4;   // 16,777,216 / 4 — exactly divisible

    // d_ws is poisoned to 0xAA before every call: zero the accumulator slots.
    hipMemsetAsync(d_ws, 0, 2 * NCLS * ACC_STRIDE * sizeof(float), stream);

    loss_main_kernel<<<1024, 256, 0, stream>>>(outputs, targets, mask, ws, n4);
    loss_final_kernel<<<1, 64, 0, stream>>>(ws, out);
}